// Round 1
// baseline (40.966 us; speedup 1.0000x reference)
//
#include <hip/hip_runtime.h>
#include <stdint.h>

#define HH 512
#define WW 512
#define CC 4
#define BB 8
#define NPIX (BB * HH * WW)   // 2097152
#define NBLK3 8192            // K_cols grid size

// min over 4 packed u8 row-distances, squared (exact integers in fp32)
__device__ __forceinline__ float row_min_sq(uint32_t v) {
    float c0 = (float)(v & 255u);
    float c1 = (float)((v >> 8) & 255u);
    float c2 = (float)((v >> 16) & 255u);
    float c3 = (float)(v >> 24);
    return fminf(fminf(c0 * c0, c1 * c1), fminf(c2 * c2, c3 * c3));
}

// ---------------------------------------------------------------------------
// K_rows: per-pixel CE + label, and per-row/per-class 1D distance (u8x4).
// One wave per image row; lane l owns columns [8l, 8l+8).
// ---------------------------------------------------------------------------
__global__ __launch_bounds__(256) void k_rows(const float* __restrict__ pred,
                                              const float* __restrict__ target,
                                              float* __restrict__ pp,
                                              uint8_t* __restrict__ lab,
                                              uint32_t* __restrict__ gout) {
    const int tid  = threadIdx.x;
    const int wid  = tid >> 6;
    const int lane = tid & 63;
    const int row  = (blockIdx.x << 2) + wid;   // 0..4095 = b*512 + i
    const int b    = row >> 9;
    const int i    = row & 511;
    const int j0   = lane << 3;
    const size_t px = ((size_t)row << 9) + (size_t)j0;                 // pixel index
    const size_t pb = ((((size_t)b * CC) * HH + (size_t)i) << 9) + j0; // pred[b][0][i][j0]

    // load pred (4 channels x 8 columns)
    float x[CC][8];
    #pragma unroll
    for (int c = 0; c < CC; ++c) {
        const float4* p = reinterpret_cast<const float4*>(pred + pb + (size_t)c * (HH * WW));
        float4 a0 = p[0], a1 = p[1];
        x[c][0] = a0.x; x[c][1] = a0.y; x[c][2] = a0.z; x[c][3] = a0.w;
        x[c][4] = a1.x; x[c][5] = a1.y; x[c][6] = a1.z; x[c][7] = a1.w;
    }

    // labels = argmax(target) (one-hot; strict > keeps first-max semantics)
    int L[8];
    {
        float tm[8];
        #pragma unroll
        for (int c = 0; c < CC; ++c) {
            const float4* p = reinterpret_cast<const float4*>(target + pb + (size_t)c * (HH * WW));
            float4 a0 = p[0], a1 = p[1];
            float tv[8] = {a0.x, a0.y, a0.z, a0.w, a1.x, a1.y, a1.z, a1.w};
            #pragma unroll
            for (int jj = 0; jj < 8; ++jj) {
                if (c == 0) { tm[jj] = tv[jj]; L[jj] = 0; }
                else if (tv[jj] > tm[jj]) { tm[jj] = tv[jj]; L[jj] = c; }
            }
        }
    }

    // per-pixel cross entropy: lse - pred[label]
    float ppv[8];
    #pragma unroll
    for (int jj = 0; jj < 8; ++jj) {
        float m = fmaxf(fmaxf(x[0][jj], x[1][jj]), fmaxf(x[2][jj], x[3][jj]));
        float s = __expf(x[0][jj] - m) + __expf(x[1][jj] - m) +
                  __expf(x[2][jj] - m) + __expf(x[3][jj] - m);
        float xs = (L[jj] == 0) ? x[0][jj] : (L[jj] == 1) ? x[1][jj]
                 : (L[jj] == 2) ? x[2][jj] : x[3][jj];
        ppv[jj] = (m + __logf(s)) - xs;
    }
    float4* ppo = reinterpret_cast<float4*>(pp + px);
    ppo[0] = make_float4(ppv[0], ppv[1], ppv[2], ppv[3]);
    ppo[1] = make_float4(ppv[4], ppv[5], ppv[6], ppv[7]);

    uint32_t llo = (uint32_t)L[0] | ((uint32_t)L[1] << 8) | ((uint32_t)L[2] << 16) | ((uint32_t)L[3] << 24);
    uint32_t lhi = (uint32_t)L[4] | ((uint32_t)L[5] << 8) | ((uint32_t)L[6] << 16) | ((uint32_t)L[7] << 24);
    *reinterpret_cast<uint2*>(lab + px) = make_uint2(llo, lhi);

    // per-class 1D row distance via wave prefix scans
    uint32_t gp[8] = {0, 0, 0, 0, 0, 0, 0, 0};
    #pragma unroll
    for (int c = 0; c < CC; ++c) {
        // left: last feature index <= j
        int run = -1000000;
        int lastL[8];
        #pragma unroll
        for (int jj = 0; jj < 8; ++jj) { if (L[jj] == c) run = j0 + jj; lastL[jj] = run; }
        int incl = run;
        #pragma unroll
        for (int d = 1; d < 64; d <<= 1) {
            int up = __shfl_up(incl, (unsigned)d, 64);
            if (lane >= d) incl = max(incl, up);
        }
        int excl = __shfl_up(incl, 1u, 64);
        if (lane == 0) excl = -1000000;

        // right: next feature index >= j
        int nrun = 1000000;
        int nxtL[8];
        #pragma unroll
        for (int jj = 7; jj >= 0; --jj) { if (L[jj] == c) nrun = j0 + jj; nxtL[jj] = nrun; }
        int rincl = nrun;
        #pragma unroll
        for (int d = 1; d < 64; d <<= 1) {
            int dn = __shfl_down(rincl, (unsigned)d, 64);
            if (lane < 64 - d) rincl = min(rincl, dn);
        }
        int rexcl = __shfl_down(rincl, 1u, 64);
        if (lane == 63) rexcl = 1000000;

        #pragma unroll
        for (int jj = 0; jj < 8; ++jj) {
            int last = max(lastL[jj], excl);
            int nxt  = min(nxtL[jj], rexcl);
            int dl = (j0 + jj) - last;
            int dr = nxt - (j0 + jj);
            int gg = min(min(dl, dr), 255);   // >255 -> exp(-1300)=0 either way
            gp[jj] |= ((uint32_t)gg) << (c * 8);
        }
    }
    uint4* go = reinterpret_cast<uint4*>(gout + px);
    go[0] = make_uint4(gp[0], gp[1], gp[2], gp[3]);
    go[1] = make_uint4(gp[4], gp[5], gp[6], gp[7]);
}

// ---------------------------------------------------------------------------
// K_cols: vertical min-plus with outward early-exit, weight, CE combine,
// per-block partial sums.
// ---------------------------------------------------------------------------
__global__ __launch_bounds__(256) void k_cols(const float* __restrict__ pp,
                                              const uint8_t* __restrict__ lab,
                                              const uint32_t* __restrict__ g,
                                              float* __restrict__ partial) {
    const int bid = blockIdx.x;          // b*1024 + i*2 + jt
    const int tid = threadIdx.x;
    const int jt = bid & 1;
    const int i  = (bid >> 1) & 511;
    const int b  = bid >> 10;
    const int j  = (jt << 8) + tid;
    const size_t px = (((size_t)(b * 512 + i)) << 9) + (size_t)j;
    const float ppx = pp[px];
    const int L = lab[px];
    const uint32_t ownmask = 255u << (L * 8);   // exclude own class (force g=255)
    const uint32_t* gb = g + (((size_t)(b * 512)) << 9) + (size_t)j;

    float best = 3.0e38f;
    for (int dk = 0; dk < 512; ++dk) {
        float dk2 = (float)(dk * dk);
        if (!__any(dk2 < best)) break;   // all future candidates >= dk^2
        int ku = i - dk;                 // block-uniform branches
        if (ku >= 0) {
            uint32_t v = gb[(size_t)ku << 9] | ownmask;
            best = fminf(best, row_min_sq(v) + dk2);
        }
        int kd = i + dk;
        if (dk > 0 && kd < 512) {
            uint32_t v = gb[(size_t)kd << 9] | ownmask;
            best = fminf(best, row_min_sq(v) + dk2);
        }
    }

    // w = 1 + 10*exp(-(0+d2)^2 / 50);  contrib = pp*(1 + w)
    float s = sqrtf(best);
    float e = __expf(-0.02f * s * s);
    float v = ppx * (2.0f + 10.0f * e);

    // block reduction
    #pragma unroll
    for (int off = 32; off > 0; off >>= 1) v += __shfl_down(v, (unsigned)off, 64);
    __shared__ float red[4];
    const int wid = tid >> 6, lane = tid & 63;
    if (lane == 0) red[wid] = v;
    __syncthreads();
    if (tid == 0) partial[bid] = (red[0] + red[1]) + (red[2] + red[3]);
}

// ---------------------------------------------------------------------------
// K_red: deterministic double-precision final reduction.
// ---------------------------------------------------------------------------
__global__ __launch_bounds__(256) void k_red(const float* __restrict__ partial,
                                             float* __restrict__ out) {
    __shared__ double sd[256];
    double a = 0.0;
    for (int idx = threadIdx.x; idx < NBLK3; idx += 256) a += (double)partial[idx];
    sd[threadIdx.x] = a;
    __syncthreads();
    #pragma unroll
    for (int s = 128; s > 0; s >>= 1) {
        if (threadIdx.x < s) sd[threadIdx.x] += sd[threadIdx.x + s];
        __syncthreads();
    }
    if (threadIdx.x == 0) out[0] = (float)(sd[0] * (1.0 / (double)NPIX));
}

extern "C" void kernel_launch(void* const* d_in, const int* in_sizes, int n_in,
                              void* d_out, int out_size, void* d_ws, size_t ws_size,
                              hipStream_t stream) {
    const float* pred   = (const float*)d_in[0];
    const float* target = (const float*)d_in[1];
    char* ws = (char*)d_ws;
    // layout: pp f32[NPIX] | lab u8[NPIX] | g u32[NPIX] | partial f32[NBLK3]
    float*    pp      = (float*)ws;                              // 8 MB
    uint8_t*  lab     = (uint8_t*)(ws + (size_t)NPIX * 4);       // 2 MB
    uint32_t* g       = (uint32_t*)(ws + (size_t)NPIX * 5);      // 8 MB
    float*    partial = (float*)(ws + (size_t)NPIX * 9);         // 32 KB
    float*    out     = (float*)d_out;

    hipLaunchKernelGGL(k_rows, dim3(4096 / 4), dim3(256), 0, stream, pred, target, pp, lab, g);
    hipLaunchKernelGGL(k_cols, dim3(NBLK3), dim3(256), 0, stream, pp, lab, g, partial);
    hipLaunchKernelGGL(k_red, dim3(1), dim3(256), 0, stream, partial, out);
}